// Round 8
// baseline (432.051 us; speedup 1.0000x reference)
//
#include <hip/hip_runtime.h>

#define NFEAT 64
#define NCAT 192
#define BN_NODES 32
#define BN_SPAN 8
#define NBLK 128
#define P4CAP 4608

typedef float f32x4 __attribute__((ext_vector_type(4)));
typedef short bf16x8 __attribute__((ext_vector_type(8)));

__device__ __forceinline__ float bf2f(unsigned int u16) {
    union { unsigned int i; float f; } c; c.i = u16 << 16; return c.f;
}
__device__ __forceinline__ unsigned short f2bf(float f) {
    union { float f; unsigned int i; } c; c.f = f;
    unsigned int r = c.i + 0x7fffu + ((c.i >> 16) & 1u);
    return (unsigned short)(r >> 16);
}

// Per-graph node counts via binary search on the sorted batch array (no atomics).
__global__ void cntb_kernel(const int* __restrict__ batch, float* __restrict__ cnt,
                            int n, int ngraphs) {
    int g = blockIdx.x * blockDim.x + threadIdx.x;
    if (g >= ngraphs) return;
    int lo = 0, hi = n;
    while (lo < hi) { int mid = (lo + hi) >> 1; if (batch[mid] < g) lo = mid + 1; else hi = mid; }
    int a = lo;
    lo = 0; hi = n;
    int g1 = g + 1;
    while (lo < hi) { int mid = (lo + hi) >> 1; if (batch[mid] < g1) lo = mid + 1; else hi = mid; }
    cnt[g] = (float)(lo - a);
}

__global__ void cvt_kernel(const float* __restrict__ x, unsigned short* __restrict__ xb, int total4) {
    int t = blockIdx.x * blockDim.x + threadIdx.x;
    if (t < total4) {
        float4 v = reinterpret_cast<const float4*>(x)[t];
        ushort4 o;
        o.x = f2bf(v.x); o.y = f2bf(v.y); o.z = f2bf(v.z); o.w = f2bf(v.w);
        reinterpret_cast<ushort4*>(xb)[t] = o;
    }
}

__global__ void wprep_kernel(const float* __restrict__ Wl0, const float* __restrict__ Wr0,
                             const float* __restrict__ Wl1, const float* __restrict__ Wr1,
                             const float* __restrict__ Wl2, const float* __restrict__ Wr2,
                             unsigned short* __restrict__ wcat) {
    int t = blockIdx.x * blockDim.x + threadIdx.x;
    if (t >= 3 * 64 * 128) return;
    int L = t >> 13;
    int r = t & 8191;
    int f = r >> 7, k = r & 127;
    const float* Wl = (L == 0) ? Wl0 : (L == 1) ? Wl1 : Wl2;
    const float* Wr = (L == 0) ? Wr0 : (L == 1) ? Wr1 : Wr2;
    float v = (k < 64) ? Wl[f * 64 + k] : Wr[f * 64 + (k - 64)];
    wcat[t] = f2bf(v);
}

// ---- CSR build as two-level counting sort (bucket = dst >> 8) ----

__global__ __launch_bounds__(256) void hist_kernel(const int* __restrict__ dst,
                                                   int* __restrict__ C, int ne, int nbuck) {
    __shared__ int hist[1024];
    int blk = blockIdx.x, tid = threadIdx.x;
    for (int t = tid; t < nbuck; t += 256) hist[t] = 0;
    __syncthreads();
    int chunk = (ne + NBLK - 1) / NBLK;
    int s = blk * chunk, e_end = min(s + chunk, ne);
    for (int e = s + tid; e < e_end; e += 256) atomicAdd(&hist[dst[e] >> 8], 1);
    __syncthreads();
    for (int t = tid; t < nbuck; t += 256) C[t * NBLK + blk] = hist[t];
}

__global__ __launch_bounds__(128) void colscan_kernel(const int* __restrict__ C,
                                                      int* __restrict__ Cs,
                                                      int* __restrict__ coltot) {
    __shared__ int wt[2];
    int b = blockIdx.x, t = threadIdx.x;
    int v = C[b * NBLK + t];
    int lane = t & 63, w = t >> 6;
    int incl = v;
#pragma unroll
    for (int off = 1; off < 64; off <<= 1) { int u = __shfl_up(incl, off); if (lane >= off) incl += u; }
    if (lane == 63) wt[w] = incl;
    __syncthreads();
    int excl = incl - v + ((w == 1) ? wt[0] : 0);
    Cs[b * NBLK + t] = excl;
    if (t == NBLK - 1) coltot[b] = excl + v;
}

__global__ __launch_bounds__(1024) void topscan_kernel(const int* __restrict__ coltot,
                                                       int* __restrict__ bucket_base,
                                                       int nbuck, int ne) {
    __shared__ int a[1024];
    int t = threadIdx.x;
    int v = (t < nbuck) ? coltot[t] : 0;
    a[t] = v;
    __syncthreads();
    for (int off = 1; off < 1024; off <<= 1) {
        int u = (t >= off) ? a[t - off] : 0;
        __syncthreads();
        a[t] += u;
        __syncthreads();
    }
    if (t < nbuck) bucket_base[t] = a[t] - v;
    if (t == 0) bucket_base[nbuck] = ne;
}

__global__ __launch_bounds__(256) void scatter3_kernel(const int* __restrict__ src,
                                                       const int* __restrict__ dst,
                                                       const int* __restrict__ Cs,
                                                       const int* __restrict__ bucket_base,
                                                       unsigned int* __restrict__ ebuf,
                                                       int ne, int nbuck) {
    __shared__ int cur[1024];
    int blk = blockIdx.x, tid = threadIdx.x;
    for (int t = tid; t < nbuck; t += 256) cur[t] = bucket_base[t] + Cs[t * NBLK + blk];
    __syncthreads();
    int chunk = (ne + NBLK - 1) / NBLK;
    int s = blk * chunk, e_end = min(s + chunk, ne);
    for (int e = s + tid; e < e_end; e += 256) {
        int sv = src[e], dv = dst[e];
        int b = dv >> 8;
        int r = atomicAdd(&cur[b], 1);
        ebuf[r] = (unsigned)sv | ((unsigned)(dv & 255) << 24);
    }
}

__global__ __launch_bounds__(256) void bucketfill_kernel(const unsigned int* __restrict__ ebuf,
                                                         const int* __restrict__ bucket_base,
                                                         int* __restrict__ row_start,
                                                         int* __restrict__ csr_src,
                                                         int n, int ne) {
    __shared__ unsigned int ed[P4CAP];
    __shared__ int deg_l[256];
    __shared__ int cur_l[256];
    __shared__ int wsum[4];
    int b = blockIdx.x, tid = threadIdx.x;
    int s = bucket_base[b];
    int cnt = bucket_base[b + 1] - s;
    deg_l[tid] = 0;
    __syncthreads();
    for (int t = tid; t < cnt; t += 256) {
        unsigned int e = ebuf[s + t];
        if (t < P4CAP) ed[t] = e;
        atomicAdd(&deg_l[e >> 24], 1);
    }
    __syncthreads();
    int v = deg_l[tid];
    int lane = tid & 63, w = tid >> 6;
    int incl = v;
#pragma unroll
    for (int off = 1; off < 64; off <<= 1) { int u = __shfl_up(incl, off); if (lane >= off) incl += u; }
    if (lane == 63) wsum[w] = incl;
    __syncthreads();
    int wofs = 0;
    for (int k = 0; k < w; ++k) wofs += wsum[k];
    int excl = wofs + incl - v;
    int node = b * 256 + tid;
    if (node < n) row_start[node] = s + excl;
    if (b == 0 && tid == 0) row_start[n] = ne;
    cur_l[tid] = excl;
    __syncthreads();
    for (int t = tid; t < cnt; t += 256) {
        unsigned int e = (t < P4CAP) ? ed[t] : ebuf[s + t];
        int d = e >> 24;
        int r = atomicAdd(&cur_l[d], 1);
        csr_src[s + r] = (int)(e & 0xFFFFFFu);
    }
}

__device__ __forceinline__ void acc8(uint4 v, float* a) {
    a[0] += bf2f(v.x & 0xffffu); a[1] += bf2f(v.x >> 16);
    a[2] += bf2f(v.y & 0xffffu); a[3] += bf2f(v.y >> 16);
    a[4] += bf2f(v.z & 0xffffu); a[5] += bf2f(v.z >> 16);
    a[6] += bf2f(v.w & 0xffffu); a[7] += bf2f(v.w >> 16);
}

// Fused mean-gather + dual-linear. One wave = one 16-node x 64-feat tile.
// Gather happens directly in MFMA A-frag layout: lane (r16, kb) owns node r16,
// features kb*8.. ; the 4 lanes of a quad cover a full 128B neighbor row with
// 2 x 16B loads each. No shfl, no LDS, no agg round-trip.
// Output h is bf16; BN stats accumulated via wave->LDS->2 atomics per block.
__global__ __launch_bounds__(256) void gl_kernel(
    const unsigned short* __restrict__ xb, const int* __restrict__ row_start,
    const int* __restrict__ csr_src,
    const unsigned short* __restrict__ wcat, const float* __restrict__ bl,
    unsigned short* __restrict__ hb, float* __restrict__ stats, int n) {
    __shared__ float red1[4][64];
    __shared__ float red2[4][64];
    int lane = threadIdx.x & 63;
    int wave = threadIdx.x >> 6;
    int tile = blockIdx.x * 4 + wave;
    int r16 = lane & 15, kb = lane >> 4;

    bf16x8 bfrag[4][4];
#pragma unroll
    for (int kt = 0; kt < 4; ++kt)
#pragma unroll
        for (int nt = 0; nt < 4; ++nt)
            bfrag[kt][nt] = *reinterpret_cast<const bf16x8*>(
                wcat + (size_t)(nt * 16 + r16) * 128 + kt * 32 + kb * 8);

    float blj[4];
#pragma unroll
    for (int nt = 0; nt < 4; ++nt) blj[nt] = bl[nt * 16 + r16];

    float s1[4] = {0.f, 0.f, 0.f, 0.f}, s2[4] = {0.f, 0.f, 0.f, 0.f};
    int nbase = tile << 4;
    if (nbase < n) {
        int node = nbase + r16;
        bool vn = node < n;
        int rs = 0, dg = 0;
        if (vn) { rs = row_start[node]; dg = row_start[node + 1] - rs; }

        float aA[8] = {0.f,0.f,0.f,0.f,0.f,0.f,0.f,0.f};
        float aB[8] = {0.f,0.f,0.f,0.f,0.f,0.f,0.f,0.f};
        for (int p = 0; p < dg; p += 2) {
            int nb0 = csr_src[rs + p];
            bool b1 = (p + 1) < dg;
            int nb1 = b1 ? csr_src[rs + p + 1] : 0;
            const uint4* r0 = reinterpret_cast<const uint4*>(xb + (size_t)nb0 * NFEAT);
            uint4 u0 = r0[kb];
            uint4 u1 = r0[kb + 4];
            uint4 w0, w1;
            if (b1) {
                const uint4* r1 = reinterpret_cast<const uint4*>(xb + (size_t)nb1 * NFEAT);
                w0 = r1[kb];
                w1 = r1[kb + 4];
            }
            acc8(u0, aA); acc8(u1, aB);
            if (b1) { acc8(w0, aA); acc8(w1, aB); }
        }
        float rm = 1.0f / (float)max(dg, 1);
        bf16x8 af0, af1;
#pragma unroll
        for (int c = 0; c < 8; ++c) {
            af0[c] = (short)f2bf(aA[c] * rm);
            af1[c] = (short)f2bf(aB[c] * rm);
        }
        size_t xrow = (size_t)min(node, n - 1) * NFEAT;
        bf16x8 af2 = *reinterpret_cast<const bf16x8*>(xb + xrow + kb * 8);
        bf16x8 af3 = *reinterpret_cast<const bf16x8*>(xb + xrow + 32 + kb * 8);

        f32x4 acc[4] = {{0.f,0.f,0.f,0.f},{0.f,0.f,0.f,0.f},{0.f,0.f,0.f,0.f},{0.f,0.f,0.f,0.f}};
#pragma unroll
        for (int nt = 0; nt < 4; ++nt) {
            acc[nt] = __builtin_amdgcn_mfma_f32_16x16x32_bf16(af0, bfrag[0][nt], acc[nt], 0, 0, 0);
            acc[nt] = __builtin_amdgcn_mfma_f32_16x16x32_bf16(af1, bfrag[1][nt], acc[nt], 0, 0, 0);
            acc[nt] = __builtin_amdgcn_mfma_f32_16x16x32_bf16(af2, bfrag[2][nt], acc[nt], 0, 0, 0);
            acc[nt] = __builtin_amdgcn_mfma_f32_16x16x32_bf16(af3, bfrag[3][nt], acc[nt], 0, 0, 0);
        }
        if (nbase + 16 <= n) {
#pragma unroll
            for (int nt = 0; nt < 4; ++nt) {
#pragma unroll
                for (int reg = 0; reg < 4; ++reg) {
                    int ni = nbase + kb * 4 + reg;
                    float v = acc[nt][reg] + blj[nt];
                    hb[(size_t)ni * NFEAT + nt * 16 + r16] = f2bf(v);
                    s1[nt] += v;
                    s2[nt] += v * v;
                }
            }
        } else {
#pragma unroll
            for (int nt = 0; nt < 4; ++nt) {
#pragma unroll
                for (int reg = 0; reg < 4; ++reg) {
                    int ni = nbase + kb * 4 + reg;
                    if (ni < n) {
                        float v = acc[nt][reg] + blj[nt];
                        hb[(size_t)ni * NFEAT + nt * 16 + r16] = f2bf(v);
                        s1[nt] += v;
                        s2[nt] += v * v;
                    }
                }
            }
        }
    }
#pragma unroll
    for (int nt = 0; nt < 4; ++nt) {
        s1[nt] += __shfl_xor(s1[nt], 16); s1[nt] += __shfl_xor(s1[nt], 32);
        s2[nt] += __shfl_xor(s2[nt], 16); s2[nt] += __shfl_xor(s2[nt], 32);
    }
    if (lane < 16) {
#pragma unroll
        for (int nt = 0; nt < 4; ++nt) {
            red1[wave][nt * 16 + lane] = s1[nt];
            red2[wave][nt * 16 + lane] = s2[nt];
        }
    }
    __syncthreads();
    if (wave == 0) {
        float t1 = red1[0][lane] + red1[1][lane] + red1[2][lane] + red1[3][lane];
        float t2 = red2[0][lane] + red2[1][lane] + red2[2][lane] + red2[3][lane];
        atomicAdd(&stats[lane], t1);
        atomicAdd(&stats[64 + lane], t2);
    }
}

// BN (training stats) + ReLU on bf16 h; emits bf16 next-layer features (if hbf)
// and pool accumulation via LDS (batch sorted).
__global__ __launch_bounds__(256) void bn_kernel(
    const unsigned short* __restrict__ h, unsigned short* __restrict__ hbf,
    const float* __restrict__ stats,
    const float* __restrict__ g, const float* __restrict__ b,
    const int* __restrict__ batch, float* __restrict__ pool,
    int colbase, int n) {
    __shared__ float pl[BN_SPAN][64];
    __shared__ int gmin_s, span_s;
    int tid = threadIdx.x;
    int j = tid & 63;
    int sub = tid >> 6;
    int nbase = blockIdx.x * BN_NODES;
    if (nbase >= n) return;

    if (tid == 0) {
        int last = min(nbase + BN_NODES, n) - 1;
        gmin_s = batch[nbase];
        span_s = batch[last] - gmin_s + 1;
    }
    __syncthreads();
    int gmin = gmin_s, span = span_s;
    bool use_lds = (span <= BN_SPAN);
    if (use_lds) {
        for (int t = tid; t < span * 64; t += 256) ((float*)pl)[t] = 0.0f;
    }
    __syncthreads();

    float invn = 1.0f / (float)n;
    float mu = stats[j] * invn;
    float var = stats[64 + j] * invn - mu * mu;
    float sc = rsqrtf(var + 1e-5f) * g[j];
    float bb = b[j];

    for (int r = sub; r < BN_NODES; r += 4) {
        int i = nbase + r;
        if (i >= n) break;
        size_t idx = (size_t)i * NFEAT + j;
        float v = fmaxf((bf2f(h[idx]) - mu) * sc + bb, 0.0f);
        if (hbf) hbf[idx] = f2bf(v);
        int gi = batch[i];
        if (use_lds) atomicAdd(&pl[gi - gmin][j], v);
        else atomicAdd(&pool[(size_t)gi * NCAT + colbase + j], v);
    }
    __syncthreads();
    if (use_lds) {
        for (int t = tid; t < span * 64; t += 256) {
            int s = t >> 6, j2 = t & 63;
            float v = pl[s][j2];
            if (v != 0.0f) atomicAdd(&pool[(size_t)(gmin + s) * NCAT + colbase + j2], v);
        }
    }
}

__global__ void final_kernel(const float* __restrict__ pool, const float* __restrict__ cnt,
                             float* __restrict__ out, int total) {
    int t = blockIdx.x * blockDim.x + threadIdx.x;
    if (t >= total) return;
    int gidx = t / NCAT;
    out[t] = pool[t] / fmaxf(cnt[gidx], 1.0f);
}

extern "C" void kernel_launch(void* const* d_in, const int* in_sizes, int n_in,
                              void* d_out, int out_size, void* d_ws, size_t ws_size,
                              hipStream_t stream) {
    const float* x = (const float*)d_in[0];
    const int* ei = (const int*)d_in[1];
    const int* batch = (const int*)d_in[2];

    const float* Wl[3], *bl[3], *Wr[3], *gm[3], *bt[3];
    for (int L = 0; L < 3; ++L) {
        Wl[L] = (const float*)d_in[3 + 5 * L + 0];
        bl[L] = (const float*)d_in[3 + 5 * L + 1];
        Wr[L] = (const float*)d_in[3 + 5 * L + 2];
        gm[L] = (const float*)d_in[3 + 5 * L + 3];
        bt[L] = (const float*)d_in[3 + 5 * L + 4];
    }

    const int n = in_sizes[0] / NFEAT;
    const int ne = in_sizes[1] / 2;
    const int ngraphs = out_size / NCAT;
    const int nbuck = (n + 255) >> 8;
    const int* src = ei;
    const int* dstp = ei + ne;

    char* wsb = (char*)d_ws;
    size_t off = 0;
    unsigned short* hb = (unsigned short*)(wsb + off);   off += (size_t)n * NFEAT * 2;
    unsigned short* xbA = (unsigned short*)(wsb + off);  off += (size_t)n * NFEAT * 2;
    unsigned short* xbB = (unsigned short*)(wsb + off);  off += (size_t)n * NFEAT * 2;
    unsigned short* wcat = (unsigned short*)(wsb + off); off += 3 * 64 * 128 * 2;
    int* csr_src = (int*)(wsb + off);    off += (size_t)ne * 4;
    unsigned int* ebuf = (unsigned int*)(wsb + off); off += (size_t)ne * 4;
    int* row_start = (int*)(wsb + off);  off += (size_t)(n + 1) * 4;
    int* C = (int*)(wsb + off);          off += (size_t)nbuck * NBLK * 4;
    int* Cs = (int*)(wsb + off);         off += (size_t)nbuck * NBLK * 4;
    int* coltot = (int*)(wsb + off);     off += (size_t)nbuck * 4;
    int* bucket_base = (int*)(wsb + off); off += (size_t)(nbuck + 1) * 4;
    float* stats3 = (float*)(wsb + off); off += 384 * 4;
    float* pool = (float*)(wsb + off);   off += (size_t)ngraphs * NCAT * 4;
    float* cntf = (float*)(wsb + off);   off += (size_t)ngraphs * 4;

    hipMemsetAsync(pool, 0, (size_t)ngraphs * NCAT * sizeof(float), stream);
    hipMemsetAsync(stats3, 0, 384 * sizeof(float), stream);

    hist_kernel<<<NBLK, 256, 0, stream>>>(dstp, C, ne, nbuck);
    colscan_kernel<<<nbuck, NBLK, 0, stream>>>(C, Cs, coltot);
    topscan_kernel<<<1, 1024, 0, stream>>>(coltot, bucket_base, nbuck, ne);
    scatter3_kernel<<<NBLK, 256, 0, stream>>>(src, dstp, Cs, bucket_base, ebuf, ne, nbuck);
    bucketfill_kernel<<<nbuck, 256, 0, stream>>>(ebuf, bucket_base, row_start, csr_src, n, ne);

    cntb_kernel<<<(ngraphs + 255) / 256, 256, 0, stream>>>(batch, cntf, n, ngraphs);
    cvt_kernel<<<((n * NFEAT / 4) + 255) / 256, 256, 0, stream>>>(x, xbA, n * NFEAT / 4);
    wprep_kernel<<<(3 * 64 * 128 + 255) / 256, 256, 0, stream>>>(
        Wl[0], Wr[0], Wl[1], Wr[1], Wl[2], Wr[2], wcat);

    const int ntiles = (n + 15) >> 4;
    const int glblocks = (ntiles + 3) / 4;
    const unsigned short* gin[3] = {xbA, xbB, xbA};
    unsigned short* gout[3] = {xbB, xbA, nullptr};
    for (int L = 0; L < 3; ++L) {
        gl_kernel<<<glblocks, 256, 0, stream>>>(gin[L], row_start, csr_src,
                                                wcat + (size_t)L * 8192, bl[L],
                                                hb, stats3 + L * 128, n);
        bn_kernel<<<(n + BN_NODES - 1) / BN_NODES, 256, 0, stream>>>(
            hb, gout[L], stats3 + L * 128, gm[L], bt[L], batch, pool, L * NFEAT, n);
    }
    final_kernel<<<(out_size + 255) / 256, 256, 0, stream>>>(pool, cntf, (float*)d_out, out_size);
}

// Round 9
// 357.611 us; speedup vs baseline: 1.2082x; 1.2082x over previous
//
#include <hip/hip_runtime.h>

#define NFEAT 64
#define NCAT 192
#define BN_NODES 32
#define BN_SPAN 8
#define NBLK 128
#define P4CAP 4608

typedef float f32x4 __attribute__((ext_vector_type(4)));
typedef short bf16x8 __attribute__((ext_vector_type(8)));

__device__ __forceinline__ float bf2f(unsigned int u16) {
    union { unsigned int i; float f; } c; c.i = u16 << 16; return c.f;
}
__device__ __forceinline__ unsigned short f2bf(float f) {
    union { float f; unsigned int i; } c; c.f = f;
    unsigned int r = c.i + 0x7fffu + ((c.i >> 16) & 1u);
    return (unsigned short)(r >> 16);
}

// Per-graph node counts via binary search on the sorted batch array (no atomics).
__global__ void cntb_kernel(const int* __restrict__ batch, float* __restrict__ cnt,
                            int n, int ngraphs) {
    int g = blockIdx.x * blockDim.x + threadIdx.x;
    if (g >= ngraphs) return;
    int lo = 0, hi = n;
    while (lo < hi) { int mid = (lo + hi) >> 1; if (batch[mid] < g) lo = mid + 1; else hi = mid; }
    int a = lo;
    lo = 0; hi = n;
    int g1 = g + 1;
    while (lo < hi) { int mid = (lo + hi) >> 1; if (batch[mid] < g1) lo = mid + 1; else hi = mid; }
    cnt[g] = (float)(lo - a);
}

__global__ void cvt_kernel(const float* __restrict__ x, unsigned short* __restrict__ xb, int total4) {
    int t = blockIdx.x * blockDim.x + threadIdx.x;
    if (t < total4) {
        float4 v = reinterpret_cast<const float4*>(x)[t];
        ushort4 o;
        o.x = f2bf(v.x); o.y = f2bf(v.y); o.z = f2bf(v.z); o.w = f2bf(v.w);
        reinterpret_cast<ushort4*>(xb)[t] = o;
    }
}

__global__ void wprep_kernel(const float* __restrict__ Wl0, const float* __restrict__ Wr0,
                             const float* __restrict__ Wl1, const float* __restrict__ Wr1,
                             const float* __restrict__ Wl2, const float* __restrict__ Wr2,
                             unsigned short* __restrict__ wcat) {
    int t = blockIdx.x * blockDim.x + threadIdx.x;
    if (t >= 3 * 64 * 128) return;
    int L = t >> 13;
    int r = t & 8191;
    int f = r >> 7, k = r & 127;
    const float* Wl = (L == 0) ? Wl0 : (L == 1) ? Wl1 : Wl2;
    const float* Wr = (L == 0) ? Wr0 : (L == 1) ? Wr1 : Wr2;
    float v = (k < 64) ? Wl[f * 64 + k] : Wr[f * 64 + (k - 64)];
    wcat[t] = f2bf(v);
}

// ---- CSR build as two-level counting sort (bucket = dst >> 8) ----

__global__ __launch_bounds__(256) void hist_kernel(const int* __restrict__ dst,
                                                   int* __restrict__ C, int ne, int nbuck) {
    __shared__ int hist[1024];
    int blk = blockIdx.x, tid = threadIdx.x;
    for (int t = tid; t < nbuck; t += 256) hist[t] = 0;
    __syncthreads();
    int chunk = (ne + NBLK - 1) / NBLK;
    int s = blk * chunk, e_end = min(s + chunk, ne);
    for (int e = s + tid; e < e_end; e += 256) atomicAdd(&hist[dst[e] >> 8], 1);
    __syncthreads();
    for (int t = tid; t < nbuck; t += 256) C[t * NBLK + blk] = hist[t];
}

__global__ __launch_bounds__(128) void colscan_kernel(const int* __restrict__ C,
                                                      int* __restrict__ Cs,
                                                      int* __restrict__ coltot) {
    __shared__ int wt[2];
    int b = blockIdx.x, t = threadIdx.x;
    int v = C[b * NBLK + t];
    int lane = t & 63, w = t >> 6;
    int incl = v;
#pragma unroll
    for (int off = 1; off < 64; off <<= 1) { int u = __shfl_up(incl, off); if (lane >= off) incl += u; }
    if (lane == 63) wt[w] = incl;
    __syncthreads();
    int excl = incl - v + ((w == 1) ? wt[0] : 0);
    Cs[b * NBLK + t] = excl;
    if (t == NBLK - 1) coltot[b] = excl + v;
}

__global__ __launch_bounds__(1024) void topscan_kernel(const int* __restrict__ coltot,
                                                       int* __restrict__ bucket_base,
                                                       int nbuck, int ne) {
    __shared__ int a[1024];
    int t = threadIdx.x;
    int v = (t < nbuck) ? coltot[t] : 0;
    a[t] = v;
    __syncthreads();
    for (int off = 1; off < 1024; off <<= 1) {
        int u = (t >= off) ? a[t - off] : 0;
        __syncthreads();
        a[t] += u;
        __syncthreads();
    }
    if (t < nbuck) bucket_base[t] = a[t] - v;
    if (t == 0) bucket_base[nbuck] = ne;
}

__global__ __launch_bounds__(256) void scatter3_kernel(const int* __restrict__ src,
                                                       const int* __restrict__ dst,
                                                       const int* __restrict__ Cs,
                                                       const int* __restrict__ bucket_base,
                                                       unsigned int* __restrict__ ebuf,
                                                       int ne, int nbuck) {
    __shared__ int cur[1024];
    int blk = blockIdx.x, tid = threadIdx.x;
    for (int t = tid; t < nbuck; t += 256) cur[t] = bucket_base[t] + Cs[t * NBLK + blk];
    __syncthreads();
    int chunk = (ne + NBLK - 1) / NBLK;
    int s = blk * chunk, e_end = min(s + chunk, ne);
    for (int e = s + tid; e < e_end; e += 256) {
        int sv = src[e], dv = dst[e];
        int b = dv >> 8;
        int r = atomicAdd(&cur[b], 1);
        ebuf[r] = (unsigned)sv | ((unsigned)(dv & 255) << 24);
    }
}

__global__ __launch_bounds__(256) void bucketfill_kernel(const unsigned int* __restrict__ ebuf,
                                                         const int* __restrict__ bucket_base,
                                                         int* __restrict__ row_start,
                                                         int* __restrict__ csr_src,
                                                         int n, int ne) {
    __shared__ unsigned int ed[P4CAP];
    __shared__ int deg_l[256];
    __shared__ int cur_l[256];
    __shared__ int wsum[4];
    int b = blockIdx.x, tid = threadIdx.x;
    int s = bucket_base[b];
    int cnt = bucket_base[b + 1] - s;
    deg_l[tid] = 0;
    __syncthreads();
    for (int t = tid; t < cnt; t += 256) {
        unsigned int e = ebuf[s + t];
        if (t < P4CAP) ed[t] = e;
        atomicAdd(&deg_l[e >> 24], 1);
    }
    __syncthreads();
    int v = deg_l[tid];
    int lane = tid & 63, w = tid >> 6;
    int incl = v;
#pragma unroll
    for (int off = 1; off < 64; off <<= 1) { int u = __shfl_up(incl, off); if (lane >= off) incl += u; }
    if (lane == 63) wsum[w] = incl;
    __syncthreads();
    int wofs = 0;
    for (int k = 0; k < w; ++k) wofs += wsum[k];
    int excl = wofs + incl - v;
    int node = b * 256 + tid;
    if (node < n) row_start[node] = s + excl;
    if (b == 0 && tid == 0) row_start[n] = ne;
    cur_l[tid] = excl;
    __syncthreads();
    for (int t = tid; t < cnt; t += 256) {
        unsigned int e = (t < P4CAP) ? ed[t] : ebuf[s + t];
        int d = e >> 24;
        int r = atomicAdd(&cur_l[d], 1);
        csr_src[s + r] = (int)(e & 0xFFFFFFu);
    }
}

// 2-VALU-per-element bf16-pair accumulate: lo = bits<<16, hi = bits & 0xffff0000.
__device__ __forceinline__ void acc8(uint4 v, float* a) {
    union { unsigned int i; float f; } c;
    c.i = v.x << 16;          a[0] += c.f;
    c.i = v.x & 0xffff0000u;  a[1] += c.f;
    c.i = v.y << 16;          a[2] += c.f;
    c.i = v.y & 0xffff0000u;  a[3] += c.f;
    c.i = v.z << 16;          a[4] += c.f;
    c.i = v.z & 0xffff0000u;  a[5] += c.f;
    c.i = v.w << 16;          a[6] += c.f;
    c.i = v.w & 0xffff0000u;  a[7] += c.f;
}

// Wave-per-node CSR mean-gather from bf16 features, up to 32 neighbors in flight
// (4 guarded 16B loads issued per lane before consumption).
__global__ __launch_bounds__(256, 8) void gather_kernel(
    const unsigned short* __restrict__ xb, const int* __restrict__ row_start,
    const int* __restrict__ csr_src, unsigned short* __restrict__ aggb, int n) {
    int lane = threadIdx.x & 63;
    int i = (blockIdx.x * blockDim.x + threadIdx.x) >> 6;
    if (i >= n) return;
    int rs = row_start[i];
    int dg = row_start[i + 1] - rs;
    int g = lane >> 3, q = lane & 7;
    const unsigned short* xq = xb + q * 8;
    float av[8];
#pragma unroll
    for (int c = 0; c < 8; ++c) av[c] = 0.0f;

    for (int base = 0; base < dg; base += 64) {
        int cnt = min(dg - base, 64);
        int myidx = (lane < cnt) ? csr_src[rs + base + lane] : 0;
        for (int p = 0; p < cnt; p += 32) {
            int s0 = p + g, s1 = s0 + 8, s2 = s0 + 16, s3 = s0 + 24;
            int nb0 = __shfl(myidx, s0);
            int nb1 = __shfl(myidx, s1);
            int nb2 = __shfl(myidx, s2);
            int nb3 = __shfl(myidx, s3);
            bool a0 = s0 < cnt, a1 = s1 < cnt, a2 = s2 < cnt, a3 = s3 < cnt;
            uint4 v0, v1, v2, v3;
            if (a0) v0 = *reinterpret_cast<const uint4*>(xq + (size_t)nb0 * NFEAT);
            if (a1) v1 = *reinterpret_cast<const uint4*>(xq + (size_t)nb1 * NFEAT);
            if (a2) v2 = *reinterpret_cast<const uint4*>(xq + (size_t)nb2 * NFEAT);
            if (a3) v3 = *reinterpret_cast<const uint4*>(xq + (size_t)nb3 * NFEAT);
            if (a0) acc8(v0, av);
            if (a1) acc8(v1, av);
            if (a2) acc8(v2, av);
            if (a3) acc8(v3, av);
        }
    }
#pragma unroll
    for (int c = 0; c < 8; ++c) {
        av[c] += __shfl_xor(av[c], 8);
        av[c] += __shfl_xor(av[c], 16);
        av[c] += __shfl_xor(av[c], 32);
    }
    if (g == 0) {
        // Lanes 0..7: av[] holds hi-feature values scaled by 2^16 mismatch? No:
        // both lo (bits<<16) and hi (bits&0xffff0000) reinterpretations are the
        // true bf16 float values, so plain mean is correct.
        float r = 1.0f / (float)max(dg, 1);
        uint4 o;
        o.x = (unsigned)f2bf(av[0] * r) | ((unsigned)f2bf(av[1] * r) << 16);
        o.y = (unsigned)f2bf(av[2] * r) | ((unsigned)f2bf(av[3] * r) << 16);
        o.z = (unsigned)f2bf(av[4] * r) | ((unsigned)f2bf(av[5] * r) << 16);
        o.w = (unsigned)f2bf(av[6] * r) | ((unsigned)f2bf(av[7] * r) << 16);
        *reinterpret_cast<uint4*>(aggb + (size_t)i * NFEAT + q * 8) = o;
    }
}

// MFMA linear: hb[n x 64] (bf16) = [aggb | xb] @ wcat^T + bl. One wave = 16-node tile.
// BN stats: wave shfl-reduce -> LDS block reduce -> 2 atomic insts per block.
__global__ __launch_bounds__(256) void lin_mfma_kernel(
    const unsigned short* __restrict__ aggb, const unsigned short* __restrict__ xb,
    const unsigned short* __restrict__ wcat, const float* __restrict__ bl,
    unsigned short* __restrict__ hb, float* __restrict__ stats, int n) {
    __shared__ float red1[4][64];
    __shared__ float red2[4][64];
    int lane = threadIdx.x & 63;
    int wave = threadIdx.x >> 6;
    int wid = (blockIdx.x * blockDim.x + threadIdx.x) >> 6;
    int nw = (gridDim.x * blockDim.x) >> 6;
    int r16 = lane & 15, kb = lane >> 4;

    bf16x8 bfrag[4][4];
#pragma unroll
    for (int kt = 0; kt < 4; ++kt)
#pragma unroll
        for (int nt = 0; nt < 4; ++nt)
            bfrag[kt][nt] = *reinterpret_cast<const bf16x8*>(
                wcat + (size_t)(nt * 16 + r16) * 128 + kt * 32 + kb * 8);

    float blj[4];
#pragma unroll
    for (int nt = 0; nt < 4; ++nt) blj[nt] = bl[nt * 16 + r16];

    float s1[4] = {0.f, 0.f, 0.f, 0.f}, s2[4] = {0.f, 0.f, 0.f, 0.f};
    int ntiles = (n + 15) >> 4;
    for (int t = wid; t < ntiles; t += nw) {
        int nbase = t << 4;
        int node = nbase + r16;
        size_t arow = (size_t)min(node, n - 1) * NFEAT;
        bf16x8 af[4];
        af[0] = *reinterpret_cast<const bf16x8*>(aggb + arow + kb * 8);
        af[1] = *reinterpret_cast<const bf16x8*>(aggb + arow + 32 + kb * 8);
        af[2] = *reinterpret_cast<const bf16x8*>(xb + arow + kb * 8);
        af[3] = *reinterpret_cast<const bf16x8*>(xb + arow + 32 + kb * 8);

        f32x4 acc[4] = {{0.f,0.f,0.f,0.f},{0.f,0.f,0.f,0.f},{0.f,0.f,0.f,0.f},{0.f,0.f,0.f,0.f}};
#pragma unroll
        for (int kt = 0; kt < 4; ++kt) {
#pragma unroll
            for (int nt = 0; nt < 4; ++nt)
                acc[nt] = __builtin_amdgcn_mfma_f32_16x16x32_bf16(af[kt], bfrag[kt][nt], acc[nt], 0, 0, 0);
        }
        if (nbase + 16 <= n) {
#pragma unroll
            for (int nt = 0; nt < 4; ++nt) {
#pragma unroll
                for (int reg = 0; reg < 4; ++reg) {
                    int ni = nbase + kb * 4 + reg;
                    float v = acc[nt][reg] + blj[nt];
                    hb[(size_t)ni * NFEAT + nt * 16 + r16] = f2bf(v);
                    s1[nt] += v;
                    s2[nt] += v * v;
                }
            }
        } else {
#pragma unroll
            for (int nt = 0; nt < 4; ++nt) {
#pragma unroll
                for (int reg = 0; reg < 4; ++reg) {
                    int ni = nbase + kb * 4 + reg;
                    if (ni < n) {
                        float v = acc[nt][reg] + blj[nt];
                        hb[(size_t)ni * NFEAT + nt * 16 + r16] = f2bf(v);
                        s1[nt] += v;
                        s2[nt] += v * v;
                    }
                }
            }
        }
    }
#pragma unroll
    for (int nt = 0; nt < 4; ++nt) {
        s1[nt] += __shfl_xor(s1[nt], 16); s1[nt] += __shfl_xor(s1[nt], 32);
        s2[nt] += __shfl_xor(s2[nt], 16); s2[nt] += __shfl_xor(s2[nt], 32);
    }
    if (lane < 16) {
#pragma unroll
        for (int nt = 0; nt < 4; ++nt) {
            red1[wave][nt * 16 + lane] = s1[nt];
            red2[wave][nt * 16 + lane] = s2[nt];
        }
    }
    __syncthreads();
    if (wave == 0) {
        float t1 = red1[0][lane] + red1[1][lane] + red1[2][lane] + red1[3][lane];
        float t2 = red2[0][lane] + red2[1][lane] + red2[2][lane] + red2[3][lane];
        atomicAdd(&stats[lane], t1);
        atomicAdd(&stats[64 + lane], t2);
    }
}

// BN (training stats) + ReLU on bf16 h; emits bf16 next-layer features (if hbf)
// and pool accumulation via LDS (batch sorted).
__global__ __launch_bounds__(256) void bn_kernel(
    const unsigned short* __restrict__ h, unsigned short* __restrict__ hbf,
    const float* __restrict__ stats,
    const float* __restrict__ g, const float* __restrict__ b,
    const int* __restrict__ batch, float* __restrict__ pool,
    int colbase, int n) {
    __shared__ float pl[BN_SPAN][64];
    __shared__ int gmin_s, span_s;
    int tid = threadIdx.x;
    int j = tid & 63;
    int sub = tid >> 6;
    int nbase = blockIdx.x * BN_NODES;
    if (nbase >= n) return;

    if (tid == 0) {
        int last = min(nbase + BN_NODES, n) - 1;
        gmin_s = batch[nbase];
        span_s = batch[last] - gmin_s + 1;
    }
    __syncthreads();
    int gmin = gmin_s, span = span_s;
    bool use_lds = (span <= BN_SPAN);
    if (use_lds) {
        for (int t = tid; t < span * 64; t += 256) ((float*)pl)[t] = 0.0f;
    }
    __syncthreads();

    float invn = 1.0f / (float)n;
    float mu = stats[j] * invn;
    float var = stats[64 + j] * invn - mu * mu;
    float sc = rsqrtf(var + 1e-5f) * g[j];
    float bb = b[j];

    for (int r = sub; r < BN_NODES; r += 4) {
        int i = nbase + r;
        if (i >= n) break;
        size_t idx = (size_t)i * NFEAT + j;
        float v = fmaxf((bf2f(h[idx]) - mu) * sc + bb, 0.0f);
        if (hbf) hbf[idx] = f2bf(v);
        int gi = batch[i];
        if (use_lds) atomicAdd(&pl[gi - gmin][j], v);
        else atomicAdd(&pool[(size_t)gi * NCAT + colbase + j], v);
    }
    __syncthreads();
    if (use_lds) {
        for (int t = tid; t < span * 64; t += 256) {
            int s = t >> 6, j2 = t & 63;
            float v = pl[s][j2];
            if (v != 0.0f) atomicAdd(&pool[(size_t)(gmin + s) * NCAT + colbase + j2], v);
        }
    }
}

__global__ void final_kernel(const float* __restrict__ pool, const float* __restrict__ cnt,
                             float* __restrict__ out, int total) {
    int t = blockIdx.x * blockDim.x + threadIdx.x;
    if (t >= total) return;
    int gidx = t / NCAT;
    out[t] = pool[t] / fmaxf(cnt[gidx], 1.0f);
}

extern "C" void kernel_launch(void* const* d_in, const int* in_sizes, int n_in,
                              void* d_out, int out_size, void* d_ws, size_t ws_size,
                              hipStream_t stream) {
    const float* x = (const float*)d_in[0];
    const int* ei = (const int*)d_in[1];
    const int* batch = (const int*)d_in[2];

    const float* Wl[3], *bl[3], *Wr[3], *gm[3], *bt[3];
    for (int L = 0; L < 3; ++L) {
        Wl[L] = (const float*)d_in[3 + 5 * L + 0];
        bl[L] = (const float*)d_in[3 + 5 * L + 1];
        Wr[L] = (const float*)d_in[3 + 5 * L + 2];
        gm[L] = (const float*)d_in[3 + 5 * L + 3];
        bt[L] = (const float*)d_in[3 + 5 * L + 4];
    }

    const int n = in_sizes[0] / NFEAT;
    const int ne = in_sizes[1] / 2;
    const int ngraphs = out_size / NCAT;
    const int nbuck = (n + 255) >> 8;
    const int* src = ei;
    const int* dstp = ei + ne;

    char* wsb = (char*)d_ws;
    size_t off = 0;
    unsigned short* hb = (unsigned short*)(wsb + off);   off += (size_t)n * NFEAT * 2;
    unsigned short* aggb = (unsigned short*)(wsb + off); off += (size_t)n * NFEAT * 2;
    unsigned short* xbA = (unsigned short*)(wsb + off);  off += (size_t)n * NFEAT * 2;
    unsigned short* xbB = (unsigned short*)(wsb + off);  off += (size_t)n * NFEAT * 2;
    unsigned short* wcat = (unsigned short*)(wsb + off); off += 3 * 64 * 128 * 2;
    int* csr_src = (int*)(wsb + off);    off += (size_t)ne * 4;
    unsigned int* ebuf = (unsigned int*)(wsb + off); off += (size_t)ne * 4;
    int* row_start = (int*)(wsb + off);  off += (size_t)(n + 1) * 4;
    int* C = (int*)(wsb + off);          off += (size_t)nbuck * NBLK * 4;
    int* Cs = (int*)(wsb + off);         off += (size_t)nbuck * NBLK * 4;
    int* coltot = (int*)(wsb + off);     off += (size_t)nbuck * 4;
    int* bucket_base = (int*)(wsb + off); off += (size_t)(nbuck + 1) * 4;
    float* stats3 = (float*)(wsb + off); off += 384 * 4;
    float* pool = (float*)(wsb + off);   off += (size_t)ngraphs * NCAT * 4;
    float* cntf = (float*)(wsb + off);   off += (size_t)ngraphs * 4;

    hipMemsetAsync(pool, 0, (size_t)ngraphs * NCAT * sizeof(float), stream);
    hipMemsetAsync(stats3, 0, 384 * sizeof(float), stream);

    hist_kernel<<<NBLK, 256, 0, stream>>>(dstp, C, ne, nbuck);
    colscan_kernel<<<nbuck, NBLK, 0, stream>>>(C, Cs, coltot);
    topscan_kernel<<<1, 1024, 0, stream>>>(coltot, bucket_base, nbuck, ne);
    scatter3_kernel<<<NBLK, 256, 0, stream>>>(src, dstp, Cs, bucket_base, ebuf, ne, nbuck);
    bucketfill_kernel<<<nbuck, 256, 0, stream>>>(ebuf, bucket_base, row_start, csr_src, n, ne);

    cntb_kernel<<<(ngraphs + 255) / 256, 256, 0, stream>>>(batch, cntf, n, ngraphs);
    cvt_kernel<<<((n * NFEAT / 4) + 255) / 256, 256, 0, stream>>>(x, xbA, n * NFEAT / 4);
    wprep_kernel<<<(3 * 64 * 128 + 255) / 256, 256, 0, stream>>>(
        Wl[0], Wr[0], Wl[1], Wr[1], Wl[2], Wr[2], wcat);

    const unsigned short* gin[3] = {xbA, xbB, xbA};
    unsigned short* gout[3] = {xbB, xbA, nullptr};
    for (int L = 0; L < 3; ++L) {
        gather_kernel<<<(n + 3) / 4, 256, 0, stream>>>(gin[L], row_start, csr_src, aggb, n);
        lin_mfma_kernel<<<256, 256, 0, stream>>>(aggb, gin[L], wcat + (size_t)L * 8192,
                                                 bl[L], hb, stats3 + L * 128, n);
        bn_kernel<<<(n + BN_NODES - 1) / BN_NODES, 256, 0, stream>>>(
            hb, gout[L], stats3 + L * 128, gm[L], bt[L], batch, pool, L * NFEAT, n);
    }
    final_kernel<<<(out_size + 255) / 256, 256, 0, stream>>>(pool, cntf, (float*)d_out, out_size);
}

// Round 10
// 261.025 us; speedup vs baseline: 1.6552x; 1.3700x over previous
//
#include <hip/hip_runtime.h>

#define NFEAT 64
#define NCAT 192
#define NBLK 128
#define P4CAP 4608

typedef float f32x4 __attribute__((ext_vector_type(4)));
typedef short bf16x8 __attribute__((ext_vector_type(8)));

__device__ __forceinline__ float bf2f(unsigned int u16) {
    union { unsigned int i; float f; } c; c.i = u16 << 16; return c.f;
}
__device__ __forceinline__ unsigned short f2bf(float f) {
    union { float f; unsigned int i; } c; c.f = f;
    unsigned int r = c.i + 0x7fffu + ((c.i >> 16) & 1u);
    return (unsigned short)(r >> 16);
}

__global__ void cvt_kernel(const float* __restrict__ x, unsigned short* __restrict__ xb, int total4) {
    int t = blockIdx.x * blockDim.x + threadIdx.x;
    if (t < total4) {
        float4 v = reinterpret_cast<const float4*>(x)[t];
        ushort4 o;
        o.x = f2bf(v.x); o.y = f2bf(v.y); o.z = f2bf(v.z); o.w = f2bf(v.w);
        reinterpret_cast<ushort4*>(xb)[t] = o;
    }
}

__global__ void wprep_kernel(const float* __restrict__ Wl0, const float* __restrict__ Wr0,
                             const float* __restrict__ Wl1, const float* __restrict__ Wr1,
                             const float* __restrict__ Wl2, const float* __restrict__ Wr2,
                             unsigned short* __restrict__ wcat) {
    int t = blockIdx.x * blockDim.x + threadIdx.x;
    if (t >= 3 * 64 * 128) return;
    int L = t >> 13;
    int r = t & 8191;
    int f = r >> 7, k = r & 127;
    const float* Wl = (L == 0) ? Wl0 : (L == 1) ? Wl1 : Wl2;
    const float* Wr = (L == 0) ? Wr0 : (L == 1) ? Wr1 : Wr2;
    float v = (k < 64) ? Wl[f * 64 + k] : Wr[f * 64 + (k - 64)];
    wcat[t] = f2bf(v);
}

// ---- CSR build as two-level counting sort (bucket = dst >> 8) ----

__global__ __launch_bounds__(256) void hist_kernel(const int* __restrict__ dst,
                                                   int* __restrict__ C, int ne, int nbuck) {
    __shared__ int hist[1024];
    int blk = blockIdx.x, tid = threadIdx.x;
    for (int t = tid; t < nbuck; t += 256) hist[t] = 0;
    __syncthreads();
    int chunk = (ne + NBLK - 1) / NBLK;
    int s = blk * chunk, e_end = min(s + chunk, ne);
    for (int e = s + tid; e < e_end; e += 256) atomicAdd(&hist[dst[e] >> 8], 1);
    __syncthreads();
    for (int t = tid; t < nbuck; t += 256) C[t * NBLK + blk] = hist[t];
}

__global__ __launch_bounds__(128) void colscan_kernel(const int* __restrict__ C,
                                                      int* __restrict__ Cs,
                                                      int* __restrict__ coltot) {
    __shared__ int wt[2];
    int b = blockIdx.x, t = threadIdx.x;
    int v = C[b * NBLK + t];
    int lane = t & 63, w = t >> 6;
    int incl = v;
#pragma unroll
    for (int off = 1; off < 64; off <<= 1) { int u = __shfl_up(incl, off); if (lane >= off) incl += u; }
    if (lane == 63) wt[w] = incl;
    __syncthreads();
    int excl = incl - v + ((w == 1) ? wt[0] : 0);
    Cs[b * NBLK + t] = excl;
    if (t == NBLK - 1) coltot[b] = excl + v;
}

__global__ __launch_bounds__(1024) void topscan_kernel(const int* __restrict__ coltot,
                                                       int* __restrict__ bucket_base,
                                                       int nbuck, int ne) {
    __shared__ int a[1024];
    int t = threadIdx.x;
    int v = (t < nbuck) ? coltot[t] : 0;
    a[t] = v;
    __syncthreads();
    for (int off = 1; off < 1024; off <<= 1) {
        int u = (t >= off) ? a[t - off] : 0;
        __syncthreads();
        a[t] += u;
        __syncthreads();
    }
    if (t < nbuck) bucket_base[t] = a[t] - v;
    if (t == 0) bucket_base[nbuck] = ne;
}

__global__ __launch_bounds__(256) void scatter3_kernel(const int* __restrict__ src,
                                                       const int* __restrict__ dst,
                                                       const int* __restrict__ Cs,
                                                       const int* __restrict__ bucket_base,
                                                       unsigned int* __restrict__ ebuf,
                                                       int ne, int nbuck) {
    __shared__ int cur[1024];
    int blk = blockIdx.x, tid = threadIdx.x;
    for (int t = tid; t < nbuck; t += 256) cur[t] = bucket_base[t] + Cs[t * NBLK + blk];
    __syncthreads();
    int chunk = (ne + NBLK - 1) / NBLK;
    int s = blk * chunk, e_end = min(s + chunk, ne);
    for (int e = s + tid; e < e_end; e += 256) {
        int sv = src[e], dv = dst[e];
        int b = dv >> 8;
        int r = atomicAdd(&cur[b], 1);
        ebuf[r] = (unsigned)sv | ((unsigned)(dv & 255) << 24);
    }
}

__global__ __launch_bounds__(256) void bucketfill_kernel(const unsigned int* __restrict__ ebuf,
                                                         const int* __restrict__ bucket_base,
                                                         int* __restrict__ row_start,
                                                         int* __restrict__ csr_src,
                                                         int n, int ne) {
    __shared__ unsigned int ed[P4CAP];
    __shared__ int deg_l[256];
    __shared__ int cur_l[256];
    __shared__ int wsum[4];
    int b = blockIdx.x, tid = threadIdx.x;
    int s = bucket_base[b];
    int cnt = bucket_base[b + 1] - s;
    deg_l[tid] = 0;
    __syncthreads();
    for (int t = tid; t < cnt; t += 256) {
        unsigned int e = ebuf[s + t];
        if (t < P4CAP) ed[t] = e;
        atomicAdd(&deg_l[e >> 24], 1);
    }
    __syncthreads();
    int v = deg_l[tid];
    int lane = tid & 63, w = tid >> 6;
    int incl = v;
#pragma unroll
    for (int off = 1; off < 64; off <<= 1) { int u = __shfl_up(incl, off); if (lane >= off) incl += u; }
    if (lane == 63) wsum[w] = incl;
    __syncthreads();
    int wofs = 0;
    for (int k = 0; k < w; ++k) wofs += wsum[k];
    int excl = wofs + incl - v;
    int node = b * 256 + tid;
    if (node < n) row_start[node] = s + excl;
    if (b == 0 && tid == 0) row_start[n] = ne;
    cur_l[tid] = excl;
    __syncthreads();
    for (int t = tid; t < cnt; t += 256) {
        unsigned int e = (t < P4CAP) ? ed[t] : ebuf[s + t];
        int d = e >> 24;
        int r = atomicAdd(&cur_l[d], 1);
        csr_src[s + r] = (int)(e & 0xFFFFFFu);
    }
}

// 2-VALU-per-element bf16-pair accumulate: lo = bits<<16, hi = bits & 0xffff0000.
__device__ __forceinline__ void acc8(uint4 v, float* a) {
    union { unsigned int i; float f; } c;
    c.i = v.x << 16;          a[0] += c.f;
    c.i = v.x & 0xffff0000u;  a[1] += c.f;
    c.i = v.y << 16;          a[2] += c.f;
    c.i = v.y & 0xffff0000u;  a[3] += c.f;
    c.i = v.z << 16;          a[4] += c.f;
    c.i = v.z & 0xffff0000u;  a[5] += c.f;
    c.i = v.w << 16;          a[6] += c.f;
    c.i = v.w & 0xffff0000u;  a[7] += c.f;
}

// Wave-per-node CSR mean-gather from bf16 features, up to 32 neighbors in flight.
__global__ __launch_bounds__(256, 8) void gather_kernel(
    const unsigned short* __restrict__ xb, const int* __restrict__ row_start,
    const int* __restrict__ csr_src, unsigned short* __restrict__ aggb, int n) {
    int lane = threadIdx.x & 63;
    int i = (blockIdx.x * blockDim.x + threadIdx.x) >> 6;
    if (i >= n) return;
    int rs = row_start[i];
    int dg = row_start[i + 1] - rs;
    int g = lane >> 3, q = lane & 7;
    const unsigned short* xq = xb + q * 8;
    float av[8];
#pragma unroll
    for (int c = 0; c < 8; ++c) av[c] = 0.0f;

    for (int base = 0; base < dg; base += 64) {
        int cnt = min(dg - base, 64);
        int myidx = (lane < cnt) ? csr_src[rs + base + lane] : 0;
        for (int p = 0; p < cnt; p += 32) {
            int s0 = p + g, s1 = s0 + 8, s2 = s0 + 16, s3 = s0 + 24;
            int nb0 = __shfl(myidx, s0);
            int nb1 = __shfl(myidx, s1);
            int nb2 = __shfl(myidx, s2);
            int nb3 = __shfl(myidx, s3);
            bool a0 = s0 < cnt, a1 = s1 < cnt, a2 = s2 < cnt, a3 = s3 < cnt;
            uint4 v0, v1, v2, v3;
            if (a0) v0 = *reinterpret_cast<const uint4*>(xq + (size_t)nb0 * NFEAT);
            if (a1) v1 = *reinterpret_cast<const uint4*>(xq + (size_t)nb1 * NFEAT);
            if (a2) v2 = *reinterpret_cast<const uint4*>(xq + (size_t)nb2 * NFEAT);
            if (a3) v3 = *reinterpret_cast<const uint4*>(xq + (size_t)nb3 * NFEAT);
            if (a0) acc8(v0, av);
            if (a1) acc8(v1, av);
            if (a2) acc8(v2, av);
            if (a3) acc8(v3, av);
        }
    }
#pragma unroll
    for (int c = 0; c < 8; ++c) {
        av[c] += __shfl_xor(av[c], 8);
        av[c] += __shfl_xor(av[c], 16);
        av[c] += __shfl_xor(av[c], 32);
    }
    if (g == 0) {
        float r = 1.0f / (float)max(dg, 1);
        uint4 o;
        o.x = (unsigned)f2bf(av[0] * r) | ((unsigned)f2bf(av[1] * r) << 16);
        o.y = (unsigned)f2bf(av[2] * r) | ((unsigned)f2bf(av[3] * r) << 16);
        o.z = (unsigned)f2bf(av[4] * r) | ((unsigned)f2bf(av[5] * r) << 16);
        o.w = (unsigned)f2bf(av[6] * r) | ((unsigned)f2bf(av[7] * r) << 16);
        *reinterpret_cast<uint4*>(aggb + (size_t)i * NFEAT + q * 8) = o;
    }
}

// MFMA linear: hb[n x 64] (bf16) = [aggb | xb] @ wcat^T + bl. One wave = 16-node tile.
// BN stats: wave shfl-reduce -> LDS block reduce -> 2 atomic insts per block.
__global__ __launch_bounds__(256) void lin_mfma_kernel(
    const unsigned short* __restrict__ aggb, const unsigned short* __restrict__ xb,
    const unsigned short* __restrict__ wcat, const float* __restrict__ bl,
    unsigned short* __restrict__ hb, float* __restrict__ stats, int n) {
    __shared__ float red1[4][64];
    __shared__ float red2[4][64];
    int lane = threadIdx.x & 63;
    int wave = threadIdx.x >> 6;
    int wid = (blockIdx.x * blockDim.x + threadIdx.x) >> 6;
    int nw = (gridDim.x * blockDim.x) >> 6;
    int r16 = lane & 15, kb = lane >> 4;

    bf16x8 bfrag[4][4];
#pragma unroll
    for (int kt = 0; kt < 4; ++kt)
#pragma unroll
        for (int nt = 0; nt < 4; ++nt)
            bfrag[kt][nt] = *reinterpret_cast<const bf16x8*>(
                wcat + (size_t)(nt * 16 + r16) * 128 + kt * 32 + kb * 8);

    float blj[4];
#pragma unroll
    for (int nt = 0; nt < 4; ++nt) blj[nt] = bl[nt * 16 + r16];

    float s1[4] = {0.f, 0.f, 0.f, 0.f}, s2[4] = {0.f, 0.f, 0.f, 0.f};
    int ntiles = (n + 15) >> 4;
    for (int t = wid; t < ntiles; t += nw) {
        int nbase = t << 4;
        int node = nbase + r16;
        size_t arow = (size_t)min(node, n - 1) * NFEAT;
        bf16x8 af[4];
        af[0] = *reinterpret_cast<const bf16x8*>(aggb + arow + kb * 8);
        af[1] = *reinterpret_cast<const bf16x8*>(aggb + arow + 32 + kb * 8);
        af[2] = *reinterpret_cast<const bf16x8*>(xb + arow + kb * 8);
        af[3] = *reinterpret_cast<const bf16x8*>(xb + arow + 32 + kb * 8);

        f32x4 acc[4] = {{0.f,0.f,0.f,0.f},{0.f,0.f,0.f,0.f},{0.f,0.f,0.f,0.f},{0.f,0.f,0.f,0.f}};
#pragma unroll
        for (int kt = 0; kt < 4; ++kt) {
#pragma unroll
            for (int nt = 0; nt < 4; ++nt)
                acc[nt] = __builtin_amdgcn_mfma_f32_16x16x32_bf16(af[kt], bfrag[kt][nt], acc[nt], 0, 0, 0);
        }
        if (nbase + 16 <= n) {
#pragma unroll
            for (int nt = 0; nt < 4; ++nt) {
#pragma unroll
                for (int reg = 0; reg < 4; ++reg) {
                    int ni = nbase + kb * 4 + reg;
                    float v = acc[nt][reg] + blj[nt];
                    hb[(size_t)ni * NFEAT + nt * 16 + r16] = f2bf(v);
                    s1[nt] += v;
                    s2[nt] += v * v;
                }
            }
        } else {
#pragma unroll
            for (int nt = 0; nt < 4; ++nt) {
#pragma unroll
                for (int reg = 0; reg < 4; ++reg) {
                    int ni = nbase + kb * 4 + reg;
                    if (ni < n) {
                        float v = acc[nt][reg] + blj[nt];
                        hb[(size_t)ni * NFEAT + nt * 16 + r16] = f2bf(v);
                        s1[nt] += v;
                        s2[nt] += v * v;
                    }
                }
            }
        }
    }
#pragma unroll
    for (int nt = 0; nt < 4; ++nt) {
        s1[nt] += __shfl_xor(s1[nt], 16); s1[nt] += __shfl_xor(s1[nt], 32);
        s2[nt] += __shfl_xor(s2[nt], 16); s2[nt] += __shfl_xor(s2[nt], 32);
    }
    if (lane < 16) {
#pragma unroll
        for (int nt = 0; nt < 4; ++nt) {
            red1[wave][nt * 16 + lane] = s1[nt];
            red2[wave][nt * 16 + lane] = s2[nt];
        }
    }
    __syncthreads();
    if (wave == 0) {
        float t1 = red1[0][lane] + red1[1][lane] + red1[2][lane] + red1[3][lane];
        float t2 = red2[0][lane] + red2[1][lane] + red2[2][lane] + red2[3][lane];
        atomicAdd(&stats[lane], t1);
        atomicAdd(&stats[64 + lane], t2);
    }
}

// Pure streaming BN+ReLU: bf16 in -> bf16 out, 8 elems/thread, scale/shift in LDS.
__global__ __launch_bounds__(256) void bn2_kernel(
    const unsigned short* __restrict__ h, unsigned short* __restrict__ hout,
    const float* __restrict__ stats, const float* __restrict__ gam,
    const float* __restrict__ bet, int n) {
    __shared__ float sc_s[64], bb_s[64];
    int tid = threadIdx.x;
    if (tid < 64) {
        float invn = 1.0f / (float)n;
        float mu = stats[tid] * invn;
        float var = stats[64 + tid] * invn - mu * mu;
        float s = rsqrtf(var + 1e-5f) * gam[tid];
        sc_s[tid] = s;
        bb_s[tid] = bet[tid] - mu * s;
    }
    __syncthreads();
    int total8 = n * 8;
    int stride = gridDim.x * blockDim.x;
    for (int t = blockIdx.x * blockDim.x + tid; t < total8; t += stride) {
        int j0 = (t & 7) * 8;
        uint4 v = reinterpret_cast<const uint4*>(h)[t];
        union { unsigned int i; float f; } c;
        float e0, e1, e2, e3, e4, e5, e6, e7;
        c.i = v.x << 16;         e0 = c.f;
        c.i = v.x & 0xffff0000u; e1 = c.f;
        c.i = v.y << 16;         e2 = c.f;
        c.i = v.y & 0xffff0000u; e3 = c.f;
        c.i = v.z << 16;         e4 = c.f;
        c.i = v.z & 0xffff0000u; e5 = c.f;
        c.i = v.w << 16;         e6 = c.f;
        c.i = v.w & 0xffff0000u; e7 = c.f;
        e0 = fmaxf(e0 * sc_s[j0 + 0] + bb_s[j0 + 0], 0.0f);
        e1 = fmaxf(e1 * sc_s[j0 + 1] + bb_s[j0 + 1], 0.0f);
        e2 = fmaxf(e2 * sc_s[j0 + 2] + bb_s[j0 + 2], 0.0f);
        e3 = fmaxf(e3 * sc_s[j0 + 3] + bb_s[j0 + 3], 0.0f);
        e4 = fmaxf(e4 * sc_s[j0 + 4] + bb_s[j0 + 4], 0.0f);
        e5 = fmaxf(e5 * sc_s[j0 + 5] + bb_s[j0 + 5], 0.0f);
        e6 = fmaxf(e6 * sc_s[j0 + 6] + bb_s[j0 + 6], 0.0f);
        e7 = fmaxf(e7 * sc_s[j0 + 7] + bb_s[j0 + 7], 0.0f);
        uint4 o;
        o.x = (unsigned)f2bf(e0) | ((unsigned)f2bf(e1) << 16);
        o.y = (unsigned)f2bf(e2) | ((unsigned)f2bf(e3) << 16);
        o.z = (unsigned)f2bf(e4) | ((unsigned)f2bf(e5) << 16);
        o.w = (unsigned)f2bf(e6) | ((unsigned)f2bf(e7) << 16);
        reinterpret_cast<uint4*>(hout)[t] = o;
    }
}

// Global mean pool straight to d_out. One block per graph (batch sorted ->
// contiguous range via binary search); 192 threads = (layer, feat).
__global__ __launch_bounds__(192) void pool_kernel(
    const unsigned short* __restrict__ h0, const unsigned short* __restrict__ h1,
    const unsigned short* __restrict__ h2, const int* __restrict__ batch,
    float* __restrict__ out, int n) {
    __shared__ int s_s, s_e;
    int g = blockIdx.x;
    int t = threadIdx.x;
    int layer = t >> 6, j = t & 63;
    const unsigned short* buf = (layer == 0) ? h0 : (layer == 1) ? h1 : h2;
    if (t == 0) {
        int lo = 0, hi = n;
        while (lo < hi) { int m = (lo + hi) >> 1; if (batch[m] < g) lo = m + 1; else hi = m; }
        s_s = lo;
        lo = 0; hi = n; int g1 = g + 1;
        while (lo < hi) { int m = (lo + hi) >> 1; if (batch[m] < g1) lo = m + 1; else hi = m; }
        s_e = lo;
    }
    __syncthreads();
    int s = s_s, e = s_e;
    float acc = 0.0f;
    int i = s;
#pragma unroll 4
    for (; i + 4 <= e; i += 4) {
        acc += bf2f(buf[(size_t)(i + 0) * NFEAT + j]);
        acc += bf2f(buf[(size_t)(i + 1) * NFEAT + j]);
        acc += bf2f(buf[(size_t)(i + 2) * NFEAT + j]);
        acc += bf2f(buf[(size_t)(i + 3) * NFEAT + j]);
    }
    for (; i < e; ++i) acc += bf2f(buf[(size_t)i * NFEAT + j]);
    float cdiv = 1.0f / (float)max(e - s, 1);
    out[(size_t)g * NCAT + t] = acc * cdiv;
}

extern "C" void kernel_launch(void* const* d_in, const int* in_sizes, int n_in,
                              void* d_out, int out_size, void* d_ws, size_t ws_size,
                              hipStream_t stream) {
    const float* x = (const float*)d_in[0];
    const int* ei = (const int*)d_in[1];
    const int* batch = (const int*)d_in[2];

    const float* Wl[3], *bl[3], *Wr[3], *gm[3], *bt[3];
    for (int L = 0; L < 3; ++L) {
        Wl[L] = (const float*)d_in[3 + 5 * L + 0];
        bl[L] = (const float*)d_in[3 + 5 * L + 1];
        Wr[L] = (const float*)d_in[3 + 5 * L + 2];
        gm[L] = (const float*)d_in[3 + 5 * L + 3];
        bt[L] = (const float*)d_in[3 + 5 * L + 4];
    }

    const int n = in_sizes[0] / NFEAT;
    const int ne = in_sizes[1] / 2;
    const int ngraphs = out_size / NCAT;
    const int nbuck = (n + 255) >> 8;
    const int* src = ei;
    const int* dstp = ei + ne;

    char* wsb = (char*)d_ws;
    size_t off = 0;
    unsigned short* hb = (unsigned short*)(wsb + off);   off += (size_t)n * NFEAT * 2;
    unsigned short* aggb = (unsigned short*)(wsb + off); off += (size_t)n * NFEAT * 2;
    unsigned short* xbA = (unsigned short*)(wsb + off);  off += (size_t)n * NFEAT * 2;
    unsigned short* xbB = (unsigned short*)(wsb + off);  off += (size_t)n * NFEAT * 2;
    unsigned short* xbC = (unsigned short*)(wsb + off);  off += (size_t)n * NFEAT * 2;
    unsigned short* wcat = (unsigned short*)(wsb + off); off += 3 * 64 * 128 * 2;
    int* csr_src = (int*)(wsb + off);    off += (size_t)ne * 4;
    unsigned int* ebuf = (unsigned int*)(wsb + off); off += (size_t)ne * 4;
    int* row_start = (int*)(wsb + off);  off += (size_t)(n + 1) * 4;
    int* C = (int*)(wsb + off);          off += (size_t)nbuck * NBLK * 4;
    int* Cs = (int*)(wsb + off);         off += (size_t)nbuck * NBLK * 4;
    int* coltot = (int*)(wsb + off);     off += (size_t)nbuck * 4;
    int* bucket_base = (int*)(wsb + off); off += (size_t)(nbuck + 1) * 4;
    float* stats3 = (float*)(wsb + off); off += 384 * 4;

    hipMemsetAsync(stats3, 0, 384 * sizeof(float), stream);

    hist_kernel<<<NBLK, 256, 0, stream>>>(dstp, C, ne, nbuck);
    colscan_kernel<<<nbuck, NBLK, 0, stream>>>(C, Cs, coltot);
    topscan_kernel<<<1, 1024, 0, stream>>>(coltot, bucket_base, nbuck, ne);
    scatter3_kernel<<<NBLK, 256, 0, stream>>>(src, dstp, Cs, bucket_base, ebuf, ne, nbuck);
    bucketfill_kernel<<<nbuck, 256, 0, stream>>>(ebuf, bucket_base, row_start, csr_src, n, ne);

    cvt_kernel<<<((n * NFEAT / 4) + 255) / 256, 256, 0, stream>>>(x, xbA, n * NFEAT / 4);
    wprep_kernel<<<(3 * 64 * 128 + 255) / 256, 256, 0, stream>>>(
        Wl[0], Wr[0], Wl[1], Wr[1], Wl[2], Wr[2], wcat);

    const unsigned short* gin[3] = {xbA, xbB, xbA};
    unsigned short* gout[3] = {xbB, xbA, xbC};
    const int bn2blocks = min((n * 8 + 255) / 256, 2048);
    for (int L = 0; L < 3; ++L) {
        gather_kernel<<<(n + 3) / 4, 256, 0, stream>>>(gin[L], row_start, csr_src, aggb, n);
        lin_mfma_kernel<<<256, 256, 0, stream>>>(aggb, gin[L], wcat + (size_t)L * 8192,
                                                 bl[L], hb, stats3 + L * 128, n);
        bn2_kernel<<<bn2blocks, 256, 0, stream>>>(hb, gout[L], stats3 + L * 128,
                                                  gm[L], bt[L], n);
    }
    pool_kernel<<<ngraphs, 192, 0, stream>>>(xbB, xbA, xbC, batch, (float*)d_out, n);
}